// Round 1
// baseline (89.118 us; speedup 1.0000x reference)
//
#include <hip/hip_runtime.h>
#include <hip/hip_bf16.h>

#define KN 32
#define DF 128
#define DP 132   // padded bf16 row stride (264 B): 8B-aligned rows, 2-way-max bank aliasing

typedef float  f32x16 __attribute__((ext_vector_type(16)));
typedef short  s16x8  __attribute__((ext_vector_type(8)));

__device__ __forceinline__ unsigned short f2bf(float x) {
    unsigned int u = __float_as_uint(x);
    return (unsigned short)((u + 0x8000u) >> 16);   // round-half-up to bf16
}
__device__ __forceinline__ float bflo(unsigned int u) { return __uint_as_float(u << 16); }
__device__ __forceinline__ float bfhi(unsigned int u) { return __uint_as_float(u & 0xffff0000u); }

__global__ __launch_bounds__(64, 2)
void coattn_kernel(const float* __restrict__ feat,
                   const int* __restrict__ sim_idx,
                   const int* __restrict__ cor_idx,
                   float* __restrict__ out, int nnodes) {
    __shared__ unsigned short Ab[KN * DP];   // Dm bf16 (sim gather)
    __shared__ unsigned short Bb[KN * DP];   // Qm bf16 (cor gather)
    __shared__ float S_sh[3 * DF];           // hsum = [S_Q, S_D, S_CQ]

    const int n = blockIdx.x;
    const int l = threadIdx.x;
    const int c = l & 31;   // row/col owned by this lane
    const int h = l >> 5;   // wave half

    const int si = sim_idx[n * KN + c];
    const int ci = cor_idx[n * KN + c];
    const float* Dr = feat + (long)si * DF;
    const float* Qr = feat + (long)ci * DF;

    // ---- Phase A: gather rows, convert to bf16; keep MFMA fragments in regs,
    //      mirror to LDS for the phase-E weighted sums.
    // Fragment layout for mfma_f32_32x32x16_bf16: lane holds row/col (l&31),
    // k = (l>>5)*8 + e within each K=16 step -> exactly d0 = s*16 + h*8 chunks.
    s16x8 af[8], bfr[8];
    #pragma unroll
    for (int s = 0; s < 8; ++s) {
        const int d0 = s * 16 + h * 8;
        float4 a0 = *(const float4*)(Dr + d0);
        float4 a1 = *(const float4*)(Dr + d0 + 4);
        float4 b0 = *(const float4*)(Qr + d0);
        float4 b1 = *(const float4*)(Qr + d0 + 4);
        union { s16x8 v; unsigned long long q[2]; } ua, ub;
        ua.v = (s16x8){ (short)f2bf(a0.x), (short)f2bf(a0.y), (short)f2bf(a0.z), (short)f2bf(a0.w),
                        (short)f2bf(a1.x), (short)f2bf(a1.y), (short)f2bf(a1.z), (short)f2bf(a1.w) };
        ub.v = (s16x8){ (short)f2bf(b0.x), (short)f2bf(b0.y), (short)f2bf(b0.z), (short)f2bf(b0.w),
                        (short)f2bf(b1.x), (short)f2bf(b1.y), (short)f2bf(b1.z), (short)f2bf(b1.w) };
        af[s] = ua.v; bfr[s] = ub.v;
        unsigned long long* pA = (unsigned long long*)&Ab[c * DP + d0];
        unsigned long long* pB = (unsigned long long*)&Bb[c * DP + d0];
        pA[0] = ua.q[0]; pA[1] = ua.q[1];
        pB[0] = ub.q[0]; pB[1] = ub.q[1];
    }

    // ---- Phase C: L = Dm*Qm^T and L^T = Qm*Dm^T (for cheap row-wise stats)
    f32x16 acc  = {0,0,0,0,0,0,0,0,0,0,0,0,0,0,0,0};
    f32x16 accT = {0,0,0,0,0,0,0,0,0,0,0,0,0,0,0,0};
    #pragma unroll
    for (int s = 0; s < 8; ++s) {
        acc  = __builtin_amdgcn_mfma_f32_32x32x16_bf16(af[s], bfr[s], acc,  0, 0, 0);
        accT = __builtin_amdgcn_mfma_f32_32x32x16_bf16(bfr[s], af[s], accT, 0, 0, 0);
    }
    // C layout: value[p] at lane = M[row=(p&3)+8*(p>>2)+4*h][col=l&31]
    // acc[p]  = L[kp(p)][c]   (kp = Dm index, c = Qm index)
    // accT[p] = L[c][jp(p)]

    // ---- Phase D: softmax stats + reduced weights w[b], v[j]
    // Column stats of L for col a=c: M_a, Z_a  (AS denominator)
    float m = acc[0];
    #pragma unroll
    for (int p = 1; p < 16; ++p) m = fmaxf(m, acc[p]);
    m = fmaxf(m, __shfl_xor(m, 32, 64));
    float z = 0.f;
    #pragma unroll
    for (int p = 0; p < 16; ++p) z += __expf(acc[p] - m);
    z += __shfl_xor(z, 32, 64);
    const float invZ = 1.0f / z;

    // Row stats of L for row b=c via accT: rowmax, rowsum (AC denominator)
    float rm = accT[0];
    #pragma unroll
    for (int p = 1; p < 16; ++p) rm = fmaxf(rm, accT[p]);
    rm = fmaxf(rm, __shfl_xor(rm, 32, 64));
    float rs = 0.f;
    #pragma unroll
    for (int p = 0; p < 16; ++p) rs += __expf(accT[p] - rm);
    rs += __shfl_xor(rs, 32, 64);
    const float invrs = 1.0f / rs;

    // w[b=c] = sum_a exp(L[b][a]-M_a)/Z_a
    float w = 0.f;
    #pragma unroll
    for (int p = 0; p < 16; ++p) {
        const int jp = (p & 3) + 8 * (p >> 2) + 4 * h;
        const float Mj  = __shfl(m,    jp, 64);
        const float iZj = __shfl(invZ, jp, 64);
        w += __expf(accT[p] - Mj) * iZj;
    }
    w += __shfl_xor(w, 32, 64);

    // v[j=c] = sum_b w[b] * exp(L[b][j]-rm_b)/rs_b
    const float wsc = w * invrs;   // lane c holds w[c]*invrs[c]
    float v = 0.f;
    #pragma unroll
    for (int p = 0; p < 16; ++p) {
        const int kp = (p & 3) + 8 * (p >> 2) + 4 * h;
        const float rmk = __shfl(rm,  kp, 64);
        const float wk  = __shfl(wsc, kp, 64);
        v += __expf(acc[p] - rmk) * wk;
    }
    v += __shfl_xor(v, 32, 64);

    // ---- Phase E: S_Q[d]=sum_j Qm[j,d], S_D[d]=sum_b w[b]Dm[b,d], S_CQ[d]=sum_j v[j]Qm[j,d]
    __syncthreads();   // LDS writes from phase A -> reads
    float sQ0 = 0.f, sQ1 = 0.f, sD0 = 0.f, sD1 = 0.f, sC0 = 0.f, sC1 = 0.f;
    #pragma unroll
    for (int b = 0; b < 32; ++b) {
        const float wb = __shfl(w, b, 64);
        const float vb = __shfl(v, b, 64);
        const unsigned int qa = *(const unsigned int*)&Ab[b * DP + 2 * l];
        const unsigned int qb = *(const unsigned int*)&Bb[b * DP + 2 * l];
        const float a0 = bflo(qa), a1 = bfhi(qa);
        const float q0 = bflo(qb), q1 = bfhi(qb);
        sQ0 += q0;                 sQ1 += q1;
        sD0 = fmaf(wb, a0, sD0);   sD1 = fmaf(wb, a1, sD1);
        sC0 = fmaf(vb, q0, sC0);   sC1 = fmaf(vb, q1, sC1);
    }

    // ---- Phase F: hsum -> AvgPool3 -> /K -> + feat
    *(float2*)&S_sh[0 * DF + 2 * l] = make_float2(sQ0, sQ1);
    *(float2*)&S_sh[1 * DF + 2 * l] = make_float2(sD0, sD1);
    *(float2*)&S_sh[2 * DF + 2 * l] = make_float2(sC0, sC1);
    __syncthreads();
    const float h0 = S_sh[6 * l + 0] + S_sh[6 * l + 1] + S_sh[6 * l + 2];
    const float h1 = S_sh[6 * l + 3] + S_sh[6 * l + 4] + S_sh[6 * l + 5];
    const float* fr = feat + (long)n * DF;
    const float o0 = fr[2 * l + 0] + h0 * (1.0f / 96.0f);
    const float o1 = fr[2 * l + 1] + h1 * (1.0f / 96.0f);
    *(float2*)&out[(long)n * DF + 2 * l] = make_float2(o0, o1);
}

extern "C" void kernel_launch(void* const* d_in, const int* in_sizes, int n_in,
                              void* d_out, int out_size, void* d_ws, size_t ws_size,
                              hipStream_t stream) {
    const float* feat = (const float*)d_in[0];
    const int* sim    = (const int*)d_in[1];
    const int* cor    = (const int*)d_in[2];
    float* out        = (float*)d_out;
    const int nnodes  = in_sizes[0] / DF;   // 20000
    hipLaunchKernelGGL(coattn_kernel, dim3(nnodes), dim3(64), 0, stream,
                       feat, sim, cor, out, nnodes);
}